// Round 8
// baseline (539.417 us; speedup 1.0000x reference)
//
#include <hip/hip_runtime.h>
#include <math.h>

#define NLEVELS 16
#define TBLSIZE 524288u   // power of two -> mod == mask
#define NPTS    524288
#define OUT_ENC_ELEMS (NPTS * NLEVELS * 2)  // 16777216 floats, then tv

typedef float f32x2 __attribute__((ext_vector_type(2)));
typedef float f32x4 __attribute__((ext_vector_type(4)));

struct LevelMeta {
    float scale[NLEVELS];
    unsigned int res[NLEVELS];
    unsigned int off[NLEVELS];
    unsigned int fhl;
};

__device__ __forceinline__ void norm_point(const float* __restrict__ pos,
                                           const float* __restrict__ bound_p,
                                           unsigned int point,
                                           float& px, float& py, float& pz)
{
    const float bound = bound_p[0];
    const float denom = 2.0f * bound;
    px = (pos[point * 3 + 0] + bound) / denom;
    py = (pos[point * 3 + 1] + bound) / denom;
    pz = (pos[point * 3 + 2] + bound) / denom;
}

// ---- Tiled levels 0..fhl-1 (tables total ~2.6MB, co-resident in L2) ----
__global__ __launch_bounds__(256) void tiled_levels_kernel(
    const float* __restrict__ pos,
    const float* __restrict__ latents,
    const float* __restrict__ bound_p,
    f32x2* __restrict__ ws,
    LevelMeta meta)
{
    const unsigned int point = blockIdx.x * 256u + threadIdx.x;
    float px, py, pz;
    norm_point(pos, bound_p, point, px, py, pz);

    const f32x2* __restrict__ lat2 = (const f32x2*)latents;

    for (unsigned int l = 0; l < meta.fhl; ++l) {
        const float scale = meta.scale[l];
        const unsigned int res = meta.res[l];
        const unsigned int off = meta.off[l];

        // Separate rounding (no FMA contraction): floor() is discontinuous.
        const float sx = __fadd_rn(__fmul_rn(px, scale), 0.5f);
        const float sy = __fadd_rn(__fmul_rn(py, scale), 0.5f);
        const float sz = __fadd_rn(__fmul_rn(pz, scale), 0.5f);
        const float fx = floorf(sx), fy = floorf(sy), fz = floorf(sz);
        const float ox = __fsub_rn(sx, fx);
        const float oy = __fsub_rn(sy, fy);
        const float oz = __fsub_rn(sz, fz);
        const unsigned int bx = (unsigned int)fx;
        const unsigned int by = (unsigned int)fy;
        const unsigned int bz = (unsigned int)fz;

        float acc0 = 0.0f, acc1 = 0.0f;
#pragma unroll
        for (int c = 0; c < 8; ++c) {
            const unsigned int c0 = (c >> 2) & 1;
            const unsigned int c1 = (c >> 1) & 1;
            const unsigned int c2 = c & 1;
            unsigned int idx = ((bx + c0) + (by + c1) * res + (bz + c2) * res * res)
                               & (TBLSIZE - 1u);
            idx += off;
            const float wx = c0 ? ox : (1.0f - ox);
            const float wy = c1 ? oy : (1.0f - oy);
            const float wz = c2 ? oz : (1.0f - oz);
            const float w = wx * wy * wz;
            const f32x2 v = lat2[idx];
            acc0 += v.x * w;
            acc1 += v.y * w;
        }
        f32x2 r; r.x = acc0; r.y = acc1;
        ws[(size_t)l * NPTS + point] = r;   // level-major, coalesced
    }
}

// ---- One hashed level per dispatch: its 4MB table is L2-resident GPU-wide ----
__global__ __launch_bounds__(256) void hash_level_kernel(
    const float* __restrict__ pos,
    const float* __restrict__ latents,
    const float* __restrict__ bound_p,
    f32x2* __restrict__ ws,
    float scale, unsigned int off, unsigned int l)
{
    const unsigned int point = blockIdx.x * 256u + threadIdx.x;
    float px, py, pz;
    norm_point(pos, bound_p, point, px, py, pz);

    const unsigned int p1 = 2654435761u;
    const unsigned int p2 = 805459861u;
    const f32x2* __restrict__ lat2 = (const f32x2*)latents;

    const float sx = __fadd_rn(__fmul_rn(px, scale), 0.5f);
    const float sy = __fadd_rn(__fmul_rn(py, scale), 0.5f);
    const float sz = __fadd_rn(__fmul_rn(pz, scale), 0.5f);
    const float fx = floorf(sx), fy = floorf(sy), fz = floorf(sz);
    const float ox = __fsub_rn(sx, fx);
    const float oy = __fsub_rn(sy, fy);
    const float oz = __fsub_rn(sz, fz);
    const unsigned int bx = (unsigned int)fx;
    const unsigned int by = (unsigned int)fy;
    const unsigned int bz = (unsigned int)fz;

    float acc0 = 0.0f, acc1 = 0.0f;
#pragma unroll
    for (int c = 0; c < 8; ++c) {
        const unsigned int c0 = (c >> 2) & 1;
        const unsigned int c1 = (c >> 1) & 1;
        const unsigned int c2 = c & 1;
        unsigned int idx = ((bx + c0) ^ ((by + c1) * p1) ^ ((bz + c2) * p2))
                           & (TBLSIZE - 1u);
        idx += off;
        const float wx = c0 ? ox : (1.0f - ox);
        const float wy = c1 ? oy : (1.0f - oy);
        const float wz = c2 ? oz : (1.0f - oz);
        const float w = wx * wy * wz;
        const f32x2 v = lat2[idx];
        acc0 += v.x * w;
        acc1 += v.y * w;
    }
    f32x2 r; r.x = acc0; r.y = acc1;
    ws[(size_t)l * NPTS + point] = r;
}

// ---- Pack: level-major ws -> point-major out rows (128B/point) ----
__global__ __launch_bounds__(256) void pack_kernel(
    const f32x2* __restrict__ ws,
    float* __restrict__ out)
{
    const unsigned int point = blockIdx.x * 256u + threadIdx.x;
    f32x4* __restrict__ o4 = (f32x4*)(out + (size_t)point * (NLEVELS * 2));
#pragma unroll
    for (int i = 0; i < 8; ++i) {
        // reads: consecutive threads -> consecutive 8B within a plane (coalesced)
        const f32x2 a = ws[(size_t)(2 * i) * NPTS + point];
        const f32x2 b = ws[(size_t)(2 * i + 1) * NPTS + point];
        f32x4 v; v.x = a.x; v.y = a.y; v.z = b.x; v.w = b.y;
        __builtin_nontemporal_store(v, &o4[i]);
    }
    if (point == 0) out[OUT_ENC_ELEMS] = 0.0f;  // tv
}

// ---- Fallback (round-7 kernel) if ws is too small ----
__global__ __launch_bounds__(256, 4) void hashgrid_encode_fallback(
    const float* __restrict__ pos,
    const float* __restrict__ latents,
    const float* __restrict__ bound_p,
    float* __restrict__ out,
    LevelMeta meta)
{
    const unsigned int point = blockIdx.x * 256u + threadIdx.x;
    float px, py, pz;
    norm_point(pos, bound_p, point, px, py, pz);

    const unsigned int p1 = 2654435761u;
    const unsigned int p2 = 805459861u;
    const f32x2* __restrict__ lat2 = (const f32x2*)latents;
    f32x2 acc[NLEVELS];

#pragma unroll
    for (int l = 0; l < NLEVELS; ++l) {
        const float scale = meta.scale[l];
        const unsigned int res = meta.res[l];
        const unsigned int off = meta.off[l];
        const bool hashed = ((unsigned int)l >= meta.fhl);

        const float sx = __fadd_rn(__fmul_rn(px, scale), 0.5f);
        const float sy = __fadd_rn(__fmul_rn(py, scale), 0.5f);
        const float sz = __fadd_rn(__fmul_rn(pz, scale), 0.5f);
        const float fx = floorf(sx), fy = floorf(sy), fz = floorf(sz);
        const float ox = __fsub_rn(sx, fx);
        const float oy = __fsub_rn(sy, fy);
        const float oz = __fsub_rn(sz, fz);
        const unsigned int bx = (unsigned int)fx;
        const unsigned int by = (unsigned int)fy;
        const unsigned int bz = (unsigned int)fz;

        float a0 = 0.0f, a1 = 0.0f;
#pragma unroll
        for (int c = 0; c < 8; ++c) {
            const unsigned int c0 = (c >> 2) & 1;
            const unsigned int c1 = (c >> 1) & 1;
            const unsigned int c2 = c & 1;
            const unsigned int vx = bx + c0;
            const unsigned int vy = by + c1;
            const unsigned int vz = bz + c2;
            unsigned int idx_t = vx + vy * res + vz * res * res;
            unsigned int idx_h = vx ^ (vy * p1) ^ (vz * p2);
            unsigned int idx = (hashed ? idx_h : idx_t) & (TBLSIZE - 1u);
            idx += off;
            const float wx = c0 ? ox : (1.0f - ox);
            const float wy = c1 ? oy : (1.0f - oy);
            const float wz = c2 ? oz : (1.0f - oz);
            const float w = wx * wy * wz;
            const f32x2 v = lat2[idx];
            a0 += v.x * w;
            a1 += v.y * w;
        }
        acc[l].x = a0; acc[l].y = a1;
        __syncthreads();
        __builtin_amdgcn_sched_barrier(0);
    }

    f32x4* __restrict__ o4 = (f32x4*)(out + (size_t)point * (NLEVELS * 2));
#pragma unroll
    for (int i = 0; i < 8; ++i) {
        f32x4 v;
        v.x = acc[2 * i].x;   v.y = acc[2 * i].y;
        v.z = acc[2 * i + 1].x; v.w = acc[2 * i + 1].y;
        __builtin_nontemporal_store(v, &o4[i]);
    }
    if (point == 0) out[OUT_ENC_ELEMS] = 0.0f;
}

extern "C" void kernel_launch(void* const* d_in, const int* in_sizes, int n_in,
                              void* d_out, int out_size, void* d_ws, size_t ws_size,
                              hipStream_t stream) {
    const float* pos     = (const float*)d_in[0];
    const float* latents = (const float*)d_in[1];
    const float* bound_p = (const float*)d_in[2];
    float* out = (float*)d_out;

    // Replicate grid_meta() exactly in double precision.
    LevelMeta meta;
    const double b = exp((log(2048.0) - log(16.0)) / 15.0);
    unsigned int off = 0;
    unsigned int fhl = 0;
    for (int i = 0; i < NLEVELS; ++i) {
        const double scale = 16.0 * pow(b, (double)i) - 1.0;
        meta.scale[i] = (float)scale;
        const unsigned int res = (unsigned int)ceil(scale) + 1u;
        meta.res[i] = res;
        unsigned int n_entries = res * res * res;
        if (n_entries <= TBLSIZE) {
            fhl = (unsigned int)(i + 1);
        } else {
            n_entries = TBLSIZE;
        }
        meta.off[i] = off;
        off += n_entries;
    }
    meta.fhl = fhl;

    const int block = 256;
    const int grid = NPTS / block;   // 2048 blocks, one thread per point
    const size_t ws_needed = (size_t)NLEVELS * NPTS * sizeof(float) * 2;  // 64MB

    if (ws_size >= ws_needed) {
        f32x2* ws = (f32x2*)d_ws;
        // 1) tiled levels together (small tables, L2 co-resident)
        hipLaunchKernelGGL(tiled_levels_kernel, dim3(grid), dim3(block), 0, stream,
                           pos, latents, bound_p, ws, meta);
        // 2) one dispatch per hashed level: stream order = GPU-wide level barrier,
        //    so each 4MB table is L2-resident in every XCD during its dispatch.
        for (unsigned int l = fhl; l < NLEVELS; ++l) {
            hipLaunchKernelGGL(hash_level_kernel, dim3(grid), dim3(block), 0, stream,
                               pos, latents, bound_p, ws,
                               meta.scale[l], meta.off[l], l);
        }
        // 3) pack level-major planes into point-major output rows
        hipLaunchKernelGGL(pack_kernel, dim3(grid), dim3(block), 0, stream, ws, out);
    } else {
        hipLaunchKernelGGL(hashgrid_encode_fallback, dim3(grid), dim3(block), 0, stream,
                           pos, latents, bound_p, out, meta);
    }
}

// Round 10
// 421.198 us; speedup vs baseline: 1.2807x; 1.2807x over previous
//
#include <hip/hip_runtime.h>
#include <math.h>

#define NLEVELS 16
#define TBLSIZE 524288u   // power of two -> mod == mask
#define NPTS    524288
#define OUT_ENC_ELEMS (NPTS * NLEVELS * 2)  // 16777216 floats, then tv
#define FHL_EXPECTED 5u   // first hash level (host-verified; fallback if mismatch)

typedef float f32x2 __attribute__((ext_vector_type(2)));
typedef float f32x4 __attribute__((ext_vector_type(4)));

struct LevelMeta {
    float scale[NLEVELS];
    unsigned int res[NLEVELS];
    unsigned int off[NLEVELS];
    unsigned int fhl;
};

__device__ __forceinline__ void norm_point(const float* __restrict__ pos,
                                           const float* __restrict__ bound_p,
                                           unsigned int point,
                                           float& px, float& py, float& pz)
{
    const float bound = bound_p[0];
    const float denom = 2.0f * bound;
    px = (pos[point * 3 + 0] + bound) / denom;
    py = (pos[point * 3 + 1] + bound) / denom;
    pz = (pos[point * 3 + 2] + bound) / denom;
}

// Per-level interpolation core. Separate rounding (no FMA contraction):
// floor() is discontinuous, contraction could flip the selected cell.
template<bool HASHED>
__device__ __forceinline__ f32x2 level_interp(
    const f32x2* __restrict__ lat2,
    float px, float py, float pz,
    float scale, unsigned int res, unsigned int off)
{
    const unsigned int p1 = 2654435761u;
    const unsigned int p2 = 805459861u;

    const float sx = __fadd_rn(__fmul_rn(px, scale), 0.5f);
    const float sy = __fadd_rn(__fmul_rn(py, scale), 0.5f);
    const float sz = __fadd_rn(__fmul_rn(pz, scale), 0.5f);
    const float fx = floorf(sx), fy = floorf(sy), fz = floorf(sz);
    const float ox = __fsub_rn(sx, fx);
    const float oy = __fsub_rn(sy, fy);
    const float oz = __fsub_rn(sz, fz);
    const unsigned int bx = (unsigned int)fx;
    const unsigned int by = (unsigned int)fy;
    const unsigned int bz = (unsigned int)fz;

    float acc0 = 0.0f, acc1 = 0.0f;
#pragma unroll
    for (int c = 0; c < 8; ++c) {
        const unsigned int c0 = (c >> 2) & 1;
        const unsigned int c1 = (c >> 1) & 1;
        const unsigned int c2 = c & 1;
        const unsigned int vx = bx + c0;
        const unsigned int vy = by + c1;
        const unsigned int vz = bz + c2;
        unsigned int idx;
        if (HASHED) idx = (vx ^ (vy * p1) ^ (vz * p2)) & (TBLSIZE - 1u);
        else        idx = (vx + vy * res + vz * res * res) & (TBLSIZE - 1u);
        idx += off;
        const float wx = c0 ? ox : (1.0f - ox);
        const float wy = c1 ? oy : (1.0f - oy);
        const float wz = c2 ? oz : (1.0f - oz);
        const float w = wx * wy * wz;
        const f32x2 v = lat2[idx];
        acc0 += v.x * w;
        acc1 += v.y * w;
    }
    f32x2 r; r.x = acc0; r.y = acc1;
    return r;
}

// ---- One hashed level per dispatch (4MB table L2-resident GPU-wide).
// 2 points/thread -> 16 independent gathers in flight (MLP).
__global__ __launch_bounds__(256) void hash_level_kernel(
    const float* __restrict__ pos,
    const float* __restrict__ latents,
    const float* __restrict__ bound_p,
    f32x2* __restrict__ ws_plane,
    float scale, unsigned int off)
{
    const unsigned int t = blockIdx.x * 256u + threadIdx.x;  // 0 .. NPTS/2-1
    const f32x2* __restrict__ lat2 = (const f32x2*)latents;

#pragma unroll
    for (int k = 0; k < 2; ++k) {
        const unsigned int point = t + (unsigned int)k * (NPTS / 2);
        float px, py, pz;
        norm_point(pos, bound_p, point, px, py, pz);
        ws_plane[point] = level_interp<true>(lat2, px, py, pz, scale, 0u, off);
    }
}

// ---- Pack + tiled levels fused: compute levels 0..4 directly (tables 2.6MB,
// L2/L3-resident), read hashed planes from ws (NT loads: streaming, keep L2
// for the tiled tables), write point-major 128B rows with PLAIN stores so L2
// merges them into full lines (round-8 NT stores caused 3x write blowup).
__global__ __launch_bounds__(256) void pack_tiled_kernel(
    const float* __restrict__ pos,
    const float* __restrict__ latents,
    const float* __restrict__ bound_p,
    const f32x2* __restrict__ ws,
    float* __restrict__ out,
    LevelMeta meta)
{
    const unsigned int point = blockIdx.x * 256u + threadIdx.x;
    const f32x2* __restrict__ lat2 = (const f32x2*)latents;

    float px, py, pz;
    norm_point(pos, bound_p, point, px, py, pz);

    f32x2 acc[NLEVELS];

    // Hashed planes first: issue the 11 independent 8B loads early.
#pragma unroll
    for (int l = FHL_EXPECTED; l < NLEVELS; ++l) {
        acc[l] = __builtin_nontemporal_load(
            &ws[(size_t)(l - FHL_EXPECTED) * NPTS + point]);
    }

    // Tiled levels: gathers from small L2-resident tables.
#pragma unroll
    for (int l = 0; l < (int)FHL_EXPECTED; ++l) {
        acc[l] = level_interp<false>(lat2, px, py, pz,
                                     meta.scale[l], meta.res[l], meta.off[l]);
    }

    f32x4* __restrict__ o4 = (f32x4*)(out + (size_t)point * (NLEVELS * 2));
#pragma unroll
    for (int i = 0; i < 8; ++i) {
        f32x4 v;
        v.x = acc[2 * i].x;     v.y = acc[2 * i].y;
        v.z = acc[2 * i + 1].x; v.w = acc[2 * i + 1].y;
        o4[i] = v;   // plain store: full 128B row merges in L2
    }
    if (point == 0) out[OUT_ENC_ELEMS] = 0.0f;  // tv
}

// ---- Fallback (round-7 monolithic) if ws too small or fhl unexpected ----
__global__ __launch_bounds__(256, 4) void hashgrid_encode_fallback(
    const float* __restrict__ pos,
    const float* __restrict__ latents,
    const float* __restrict__ bound_p,
    float* __restrict__ out,
    LevelMeta meta)
{
    const unsigned int point = blockIdx.x * 256u + threadIdx.x;
    const f32x2* __restrict__ lat2 = (const f32x2*)latents;
    float px, py, pz;
    norm_point(pos, bound_p, point, px, py, pz);

    f32x2 acc[NLEVELS];
#pragma unroll
    for (int l = 0; l < NLEVELS; ++l) {
        const bool hashed = ((unsigned int)l >= meta.fhl);
        acc[l] = hashed
            ? level_interp<true>(lat2, px, py, pz, meta.scale[l], meta.res[l], meta.off[l])
            : level_interp<false>(lat2, px, py, pz, meta.scale[l], meta.res[l], meta.off[l]);
        __syncthreads();
        __builtin_amdgcn_sched_barrier(0);
    }

    f32x4* __restrict__ o4 = (f32x4*)(out + (size_t)point * (NLEVELS * 2));
#pragma unroll
    for (int i = 0; i < 8; ++i) {
        f32x4 v;
        v.x = acc[2 * i].x;     v.y = acc[2 * i].y;
        v.z = acc[2 * i + 1].x; v.w = acc[2 * i + 1].y;
        o4[i] = v;
    }
    if (point == 0) out[OUT_ENC_ELEMS] = 0.0f;
}

extern "C" void kernel_launch(void* const* d_in, const int* in_sizes, int n_in,
                              void* d_out, int out_size, void* d_ws, size_t ws_size,
                              hipStream_t stream) {
    const float* pos     = (const float*)d_in[0];
    const float* latents = (const float*)d_in[1];
    const float* bound_p = (const float*)d_in[2];
    float* out = (float*)d_out;

    // Replicate grid_meta() exactly in double precision.
    LevelMeta meta;
    const double b = exp((log(2048.0) - log(16.0)) / 15.0);
    unsigned int off = 0;
    unsigned int fhl = 0;
    for (int i = 0; i < NLEVELS; ++i) {
        const double scale = 16.0 * pow(b, (double)i) - 1.0;
        meta.scale[i] = (float)scale;
        const unsigned int res = (unsigned int)ceil(scale) + 1u;
        meta.res[i] = res;
        unsigned int n_entries = res * res * res;
        if (n_entries <= TBLSIZE) {
            fhl = (unsigned int)(i + 1);
        } else {
            n_entries = TBLSIZE;
        }
        meta.off[i] = off;
        off += n_entries;
    }
    meta.fhl = fhl;

    const int block = 256;
    const size_t ws_needed =
        (size_t)(NLEVELS - FHL_EXPECTED) * NPTS * sizeof(float) * 2;  // 44MB

    if (fhl == FHL_EXPECTED && ws_size >= ws_needed) {
        f32x2* ws = (f32x2*)d_ws;
        // One dispatch per hashed level: stream order = GPU-wide level barrier,
        // so each 4MB table is L2-resident in every XCD during its dispatch.
        const int hgrid = (NPTS / 2) / block;   // 1024 blocks, 2 pts/thread
        for (unsigned int l = fhl; l < NLEVELS; ++l) {
            hipLaunchKernelGGL(hash_level_kernel, dim3(hgrid), dim3(block), 0, stream,
                               pos, latents, bound_p,
                               ws + (size_t)(l - fhl) * NPTS,
                               meta.scale[l], meta.off[l]);
        }
        // Tiled levels + pack in one dispatch.
        const int pgrid = NPTS / block;         // 2048 blocks
        hipLaunchKernelGGL(pack_tiled_kernel, dim3(pgrid), dim3(block), 0, stream,
                           pos, latents, bound_p, ws, out, meta);
    } else {
        const int grid = NPTS / block;
        hipLaunchKernelGGL(hashgrid_encode_fallback, dim3(grid), dim3(block), 0, stream,
                           pos, latents, bound_p, out, meta);
    }
}